// Round 3
// baseline (573.675 us; speedup 1.0000x reference)
//
#include <hip/hip_runtime.h>
#include <cmath>

// ---------------------------------------------------------------------------
// Gemma4 audio attention, MI355X bf16-MFMA pipeline.
// B=2 S=8192 HID=1024 H=8 D=128 CHUNK=128 PAST=127 FUT=128 CTX=383 POS=384
// R3: R2's fragment-order bds (coalesced bf16x8 loads in attn) but per-b bds
//     buffer + attnout aliased onto hs_bf  ->  workspace ~199 MB (R2's 283 MB
//     overflowed ws_size and memory-faulted).
// ---------------------------------------------------------------------------

using bf16x8 = __attribute__((ext_vector_type(8))) short;
using f32x4  = __attribute__((ext_vector_type(4))) float;
using s16x4  = __attribute__((ext_vector_type(4))) short;

__device__ __forceinline__ short f2bf(float f) {
  unsigned u = __float_as_uint(f);
  u = (u + 0x7FFF + ((u >> 16) & 1)) >> 16;   // RNE
  return (short)u;
}
__device__ __forceinline__ float bf2f(unsigned short s) {
  return __uint_as_float(((unsigned)s) << 16);
}

// async global->LDS, 16B per lane. LDS dest must be wave-uniform base + lane*16.
__device__ __forceinline__ void gl16(void* lds, const void* gptr) {
  __builtin_amdgcn_global_load_lds(
      (const __attribute__((address_space(1))) unsigned int*)gptr,
      (__attribute__((address_space(3))) unsigned int*)lds, 16, 0, 0);
}

// ---------------------------------------------------------------------------
// elementwise fp32 -> bf16
__global__ void cvt_bf16_k(const float* __restrict__ in, short* __restrict__ out, int n) {
  int i = (blockIdx.x * 256 + threadIdx.x) * 4;
  if (i + 3 < n) {
    float4 v = *(const float4*)&in[i];
    s16x4 o;
    o[0] = f2bf(v.x); o[1] = f2bf(v.y); o[2] = f2bf(v.z); o[3] = f2bf(v.w);
    *(s16x4*)&out[i] = o;
  }
}

// W (1024x1024 f32, [k][n]) -> Wt (bf16, [n][k])
__global__ void wtrans_k(const float* __restrict__ W, short* __restrict__ Wt) {
  __shared__ float T[64 * 65];
  const int tid = threadIdx.x;
  const int bx = blockIdx.x, by = blockIdx.y; // bx: n-tile, by: k-tile
#pragma unroll
  for (int it = 0; it < 4; ++it) {
    int ci = it * 256 + tid;
    int k = ci >> 4, n4 = (ci & 15) * 4;
    float4 v = *(const float4*)&W[(size_t)(by * 64 + k) * 1024 + bx * 64 + n4];
    T[k * 65 + n4 + 0] = v.x;
    T[k * 65 + n4 + 1] = v.y;
    T[k * 65 + n4 + 2] = v.z;
    T[k * 65 + n4 + 3] = v.w;
  }
  __syncthreads();
#pragma unroll
  for (int it = 0; it < 2; ++it) {
    int co = it * 256 + tid;
    int nn = co >> 3, k8 = (co & 7) * 8;
    bf16x8 o;
#pragma unroll
    for (int jj = 0; jj < 8; ++jj) o[jj] = f2bf(T[(k8 + jj) * 65 + nn]);
    *(bf16x8*)&Wt[(size_t)(bx * 64 + nn) * 1024 + by * 64 + k8] = o;
  }
}

// qscale[d] = (1/sqrt(128))/ln2 * softplus(pds[d])
__global__ void qscale_k(const float* __restrict__ pds, float* __restrict__ qs, double qsb) {
  int d = threadIdx.x;
  double x = (double)pds[d];
  qs[d] = (float)(qsb * log1p(exp(x)));
}

// zero vpadT pad columns: keys [0,127) and [8319,8448)
__global__ void vpadzero_k(short* __restrict__ vpadT) {
  int row = blockIdx.x;                 // (b*8+h)*128 + d   (2048 rows)
  int t = threadIdx.x;                  // 256
  int key = (t < 127) ? t : (8192 + t); // 0..126 and 8319..8447
  vpadT[(size_t)row * 8448 + key] = 0;
}

// ---------------------------------------------------------------------------
// C = A(bf16,[M][1024]) @ Bt(bf16,[1024][1024], row=n col=k)^T
// MODE 0=Q 1=K 2=V(transpose epi) 3=REL 4=POST(f32 out)
template <int MODE>
__global__ __launch_bounds__(256, 2)
void gemm_bt_k(const short* __restrict__ A, const short* __restrict__ Bt,
               short* __restrict__ outs, float* __restrict__ outf,
               const float* __restrict__ qsc, float kscale) {
  __shared__ __align__(16) short As[128 * 32];
  __shared__ __align__(16) short Bs[128 * 32];
  __shared__ __align__(16) short Tv[(MODE == 2) ? (128 * 136) : 16];

  const int tid = threadIdx.x;
  const int lane = tid & 63, wid = tid >> 6;
  const int q4 = lane >> 4, l16 = lane & 15;
  const int wr = wid >> 1, wc = wid & 1;
  const int m0 = blockIdx.x * 128, n0 = blockIdx.y * 128;

  const f32x4 z4 = {0.f, 0.f, 0.f, 0.f};
  f32x4 acc[4][4];
#pragma unroll
  for (int i = 0; i < 4; ++i)
#pragma unroll
    for (int j = 0; j < 4; ++j) acc[i][j] = z4;

  const int r0 = tid >> 2, s0_ = (tid & 3) * 8;

  for (int kk = 0; kk < 1024; kk += 32) {
    __syncthreads();
    gl16(&As[tid * 8],         A  + (size_t)(m0 + r0) * 1024 + kk + s0_);
    gl16(&Bs[tid * 8],         Bt + (size_t)(n0 + r0) * 1024 + kk + s0_);
    gl16(&As[(256 + tid) * 8], A  + (size_t)(m0 + 64 + r0) * 1024 + kk + s0_);
    gl16(&Bs[(256 + tid) * 8], Bt + (size_t)(n0 + 64 + r0) * 1024 + kk + s0_);
    __syncthreads();
    bf16x8 af[4], bfv[4];
#pragma unroll
    for (int i = 0; i < 4; ++i)
      af[i] = *(const bf16x8*)&As[(wr * 64 + i * 16 + l16) * 32 + q4 * 8];
#pragma unroll
    for (int j = 0; j < 4; ++j)
      bfv[j] = *(const bf16x8*)&Bs[(wc * 64 + j * 16 + l16) * 32 + q4 * 8];
#pragma unroll
    for (int i = 0; i < 4; ++i)
#pragma unroll
      for (int j = 0; j < 4; ++j)
        acc[i][j] = __builtin_amdgcn_mfma_f32_16x16x32_bf16(af[i], bfv[j], acc[i][j], 0, 0, 0);
  }

  float qsv[4];
  if (MODE == 0) {
#pragma unroll
    for (int j = 0; j < 4; ++j) qsv[j] = qsc[wc * 64 + j * 16 + l16];
  }

#pragma unroll
  for (int i = 0; i < 4; ++i) {
#pragma unroll
    for (int j = 0; j < 4; ++j) {
#pragma unroll
      for (int rg = 0; rg < 4; ++rg) {
        const int row = m0 + wr * 64 + i * 16 + q4 * 4 + rg;
        const int col = n0 + wc * 64 + j * 16 + l16;
        const float v = acc[i][j][rg];
        if (MODE == 0) {           // Q -> q_bf[(b*64+n)*8+h][c][d] * qscale[d]
          int b = row >> 13, s = row & 8191;
          int n = s >> 7, c = s & 127;
          int h = col >> 7, d = col & 127;
          outs[((size_t)(((b * 64 + n) * 8 + h) * 128 + c)) * 128 + d] = f2bf(v * qsv[j]);
        } else if (MODE == 1) {    // K -> kpad[b][h][127+s][d] * kscale
          int b = row >> 13, s = row & 8191;
          int h = col >> 7, d = col & 127;
          outs[((size_t)(b * 8 + h) * 8448 + 127 + s) * 128 + d] = f2bf(v * kscale);
        } else if (MODE == 2) {    // V -> LDS transpose tile
          int dl = wc * 64 + j * 16 + l16;
          int sl = wr * 64 + i * 16 + q4 * 4 + rg;
          Tv[dl * 136 + sl] = f2bf(v);
        } else if (MODE == 3) {    // REL -> relk[h][p][d]
          int h = col >> 7, d = col & 127;
          outs[(size_t)(h * 384 + row) * 128 + d] = f2bf(v);
        } else {                   // POST -> f32 out
          outf[(size_t)row * 1024 + col] = v;
        }
      }
    }
  }

  if (MODE == 2) {
    __syncthreads();
    const int b = m0 >> 13, ss = m0 & 8191, h = n0 >> 7;
#pragma unroll
    for (int it = 0; it < 8; ++it) {
      int co = it * 256 + tid;
      int d = co >> 4, s8 = (co & 15) * 8;
      *(bf16x8*)&outs[((size_t)(b * 8 + h) * 128 + d) * 8448 + 127 + ss + s8] =
          *(const bf16x8*)&Tv[d * 136 + s8];
    }
  }
}

// ---------------------------------------------------------------------------
// bdo = q_tile(128x128) @ relk[h](384x128)^T, rel-shift applied in epilogue,
// stored in MFMA-fragment order for attn_k:
//   bds[nh][t][j][ (wa*64 + qa*16 + ll) ][ ia*4 + ra ]  (8 shorts per lane slot)
// where for destination (c,k): t=k>>7, j=(k>>4)&7, ll=k&15,
//                              wa=c>>5, ia=(c>>4)&1, qa=(c>>2)&3, ra=c&3.
__global__ __launch_bounds__(256, 2)
void bd_gemm_k(const short* __restrict__ qb_b, const short* __restrict__ relk,
               short* __restrict__ bds) {
  __shared__ __align__(16) short As[128 * 32];
  __shared__ __align__(16) short Bs[128 * 32];
  const int tid = threadIdx.x;
  const int lane = tid & 63, wid = tid >> 6;
  const int q4 = lane >> 4, l16 = lane & 15;
  const int wr = wid >> 1, wc = wid & 1;
  const int p0 = blockIdx.x * 128;
  const int nh = blockIdx.y;          // n*8 + h  (within b)
  const int h = nh & 7;
  const short* A = qb_b + (size_t)nh * 16384;
  const short* Bt = relk + (size_t)h * (384 * 128);
  short* bdo = bds + (size_t)nh * 49152;

  const f32x4 z4 = {0.f, 0.f, 0.f, 0.f};
  f32x4 acc[4][4];
#pragma unroll
  for (int i = 0; i < 4; ++i)
#pragma unroll
    for (int j = 0; j < 4; ++j) acc[i][j] = z4;

  const int r0 = tid >> 2, s0_ = (tid & 3) * 8;
  for (int kk = 0; kk < 128; kk += 32) {
    __syncthreads();
    gl16(&As[tid * 8],         A  + (size_t)r0 * 128 + kk + s0_);
    gl16(&Bs[tid * 8],         Bt + (size_t)(p0 + r0) * 128 + kk + s0_);
    gl16(&As[(256 + tid) * 8], A  + (size_t)(64 + r0) * 128 + kk + s0_);
    gl16(&Bs[(256 + tid) * 8], Bt + (size_t)(p0 + 64 + r0) * 128 + kk + s0_);
    __syncthreads();
    bf16x8 af[4], bfv[4];
#pragma unroll
    for (int i = 0; i < 4; ++i)
      af[i] = *(const bf16x8*)&As[(wr * 64 + i * 16 + l16) * 32 + q4 * 8];
#pragma unroll
    for (int j = 0; j < 4; ++j)
      bfv[j] = *(const bf16x8*)&Bs[(wc * 64 + j * 16 + l16) * 32 + q4 * 8];
#pragma unroll
    for (int i = 0; i < 4; ++i)
#pragma unroll
      for (int j = 0; j < 4; ++j)
        acc[i][j] = __builtin_amdgcn_mfma_f32_16x16x32_bf16(af[i], bfv[j], acc[i][j], 0, 0, 0);
  }

  // rel-shift: (r,p) -> (c,k): flat r*384+p == c*383+k, drop c >= 128
#pragma unroll
  for (int i = 0; i < 4; ++i)
#pragma unroll
    for (int j = 0; j < 4; ++j)
#pragma unroll
      for (int rg = 0; rg < 4; ++rg) {
        int r = wr * 64 + i * 16 + q4 * 4 + rg;
        int p = p0 + wc * 64 + j * 16 + l16;
        int t = r + p;
        int c = (t < 383) ? r : (r + 1);
        int k = (t < 383) ? t : (t - 383);
        if (c < 128) {
          int tt = k >> 7, jj = (k >> 4) & 7, ll = k & 15;
          int wa = c >> 5, ia = (c >> 4) & 1, qa = (c >> 2) & 3, ra = c & 3;
          bdo[((((size_t)tt * 8 + jj) * 256) + wa * 64 + qa * 16 + ll) * 8 + ia * 4 + ra] =
              f2bf(acc[i][j][rg]);
        }
      }
}

// ---------------------------------------------------------------------------
// fused local attention: one WG per (n,h) for fixed b.
__global__ __launch_bounds__(256, 2)
void attn_k(const short* __restrict__ qb_b, const short* __restrict__ kpad,
            const short* __restrict__ vpadT, const short* __restrict__ bds,
            short* __restrict__ attnout, int b) {
  __shared__ __align__(16) short Ks[4 * 128 * 32]; // slabs [dc][row][32], reused Q->K->V
  __shared__ __align__(16) short Ps[2 * 128 * 40]; // 2 key-slabs of 32, padded stride 40

  const int tid = threadIdx.x;
  const int lane = tid & 63, wid = tid >> 6;
  const int q4 = lane >> 4, l16 = lane & 15;
  const int bx = blockIdx.x;          // n*8 + h
  const int n = bx >> 3, h = bx & 7;

  const short* qtile = qb_b + (size_t)bx * 16384;
  const short* kbase = kpad + ((size_t)(b * 8 + h) * 8448 + n * 128) * 128;
  const short* vtb = vpadT + (size_t)(b * 8 + h) * 128 * 8448 + n * 128;
  const short* bdb = bds + (size_t)bx * 49152;

  // stage Q into Ks slabs, pull fragments to registers
#pragma unroll
  for (int it = 0; it < 8; ++it) {
    int ci = it * 256 + tid;
    int dc = ci >> 9, rr = (ci >> 2) & 127, sub = (ci & 3) * 8;
    gl16(&Ks[ci * 8], qtile + rr * 128 + dc * 32 + sub);
  }
  __syncthreads();
  bf16x8 qf[2][4];
#pragma unroll
  for (int i = 0; i < 2; ++i)
#pragma unroll
    for (int dc = 0; dc < 4; ++dc)
      qf[i][dc] = *(const bf16x8*)&Ks[dc * 4096 + (wid * 32 + i * 16 + l16) * 32 + q4 * 8];

  const f32x4 z4 = {0.f, 0.f, 0.f, 0.f};
  f32x4 acco[2][8];
#pragma unroll
  for (int i = 0; i < 2; ++i)
#pragma unroll
    for (int j = 0; j < 8; ++j) acco[i][j] = z4;
  float rsum[2][4] = {};

  for (int t = 0; t < 3; ++t) {
    __syncthreads();  // Ks/Ps reusable
#pragma unroll
    for (int it = 0; it < 8; ++it) {  // stage K tile
      int ci = it * 256 + tid;
      int dc = ci >> 9, rr = (ci >> 2) & 127, sub = (ci & 3) * 8;
      gl16(&Ks[ci * 8], kbase + (size_t)(t * 128 + rr) * 128 + dc * 32 + sub);
    }

    // coalesced bd fragment loads for this t (overlap with K staging wait)
    bf16x8 bdv[8];
#pragma unroll
    for (int j = 0; j < 8; ++j)
      bdv[j] = *(const bf16x8*)&bdb[(((size_t)t * 8 + j) * 256 + wid * 64 + lane) * 8];

    __syncthreads();

    // S = Q @ K^T
    f32x4 accs[2][8];
#pragma unroll
    for (int i = 0; i < 2; ++i)
#pragma unroll
      for (int j = 0; j < 8; ++j) accs[i][j] = z4;
#pragma unroll
    for (int dc = 0; dc < 4; ++dc) {
      bf16x8 kf[8];
#pragma unroll
      for (int j = 0; j < 8; ++j)
        kf[j] = *(const bf16x8*)&Ks[dc * 4096 + (j * 16 + l16) * 32 + q4 * 8];
#pragma unroll
      for (int i = 0; i < 2; ++i)
#pragma unroll
        for (int j = 0; j < 8; ++j)
          accs[i][j] = __builtin_amdgcn_mfma_f32_16x16x32_bf16(qf[i][dc], kf[j], accs[i][j], 0, 0, 0);
    }

    // logits: s = ac + bd;  w = exp2(-100*log2e / (exp2(s*2*log2e/50) + 1))
#pragma unroll
    for (int i = 0; i < 2; ++i) {
#pragma unroll
      for (int j = 0; j < 8; ++j) {
        const int kg = t * 128 + j * 16 + l16;
#pragma unroll
        for (int rg = 0; rg < 4; ++rg) {
          float sv = accs[i][j][rg] + bf2f((unsigned short)bdv[j][i * 4 + rg]);
          float tt = exp2f(sv * 0.057707801635558534f);
          float wgt = exp2f(-144.26950408889634f * __fdividef(1.0f, tt + 1.0f));
          wgt = (kg < 383) ? wgt : 0.0f;
          accs[i][j][rg] = wgt;
          rsum[i][rg] += wgt;
        }
      }
    }
    __syncthreads();  // all waves done reading Ks (K tile)

    // stage V^T tile into Ks slabs [kc][d][32keys]
#pragma unroll
    for (int it = 0; it < 8; ++it) {
      int ci = it * 256 + tid;
      int kc = ci >> 9, dd = (ci >> 2) & 127, sub = (ci & 3) * 8;
      gl16(&Ks[ci * 8], vtb + (size_t)dd * 8448 + t * 128 + kc * 32 + sub);
    }
    // P half 0 (keys 0..63)
#pragma unroll
    for (int i = 0; i < 2; ++i)
#pragma unroll
      for (int j = 0; j < 4; ++j)
#pragma unroll
        for (int rg = 0; rg < 4; ++rg) {
          int c = wid * 32 + i * 16 + q4 * 4 + rg;
          int kl = j * 16 + l16;
          Ps[((kl >> 5) & 1) * 5120 + c * 40 + (kl & 31)] = f2bf(accs[i][j][rg]);
        }
    __syncthreads();
    // PV kc = 0,1
#pragma unroll
    for (int kc = 0; kc < 2; ++kc) {
      bf16x8 pf[2], vf[8];
#pragma unroll
      for (int i = 0; i < 2; ++i)
        pf[i] = *(const bf16x8*)&Ps[(kc & 1) * 5120 + (wid * 32 + i * 16 + l16) * 40 + q4 * 8];
#pragma unroll
      for (int j = 0; j < 8; ++j)
        vf[j] = *(const bf16x8*)&Ks[kc * 4096 + (j * 16 + l16) * 32 + q4 * 8];
#pragma unroll
      for (int i = 0; i < 2; ++i)
#pragma unroll
        for (int j = 0; j < 8; ++j)
          acco[i][j] = __builtin_amdgcn_mfma_f32_16x16x32_bf16(pf[i], vf[j], acco[i][j], 0, 0, 0);
    }
    __syncthreads();
    // P half 1 (keys 64..127)
#pragma unroll
    for (int i = 0; i < 2; ++i)
#pragma unroll
      for (int j = 4; j < 8; ++j)
#pragma unroll
        for (int rg = 0; rg < 4; ++rg) {
          int c = wid * 32 + i * 16 + q4 * 4 + rg;
          int kl = j * 16 + l16;
          Ps[((kl >> 5) & 1) * 5120 + c * 40 + (kl & 31)] = f2bf(accs[i][j][rg]);
        }
    __syncthreads();
    // PV kc = 2,3
#pragma unroll
    for (int kc = 2; kc < 4; ++kc) {
      bf16x8 pf[2], vf[8];
#pragma unroll
      for (int i = 0; i < 2; ++i)
        pf[i] = *(const bf16x8*)&Ps[(kc & 1) * 5120 + (wid * 32 + i * 16 + l16) * 40 + q4 * 8];
#pragma unroll
      for (int j = 0; j < 8; ++j)
        vf[j] = *(const bf16x8*)&Ks[kc * 4096 + (j * 16 + l16) * 32 + q4 * 8];
#pragma unroll
      for (int i = 0; i < 2; ++i)
#pragma unroll
        for (int j = 0; j < 8; ++j)
          acco[i][j] = __builtin_amdgcn_mfma_f32_16x16x32_bf16(pf[i], vf[j], acco[i][j], 0, 0, 0);
    }
  }

  // row-sum butterfly over the 16-lane group (cols), normalize, write bf16
  float rinv[2][4];
#pragma unroll
  for (int i = 0; i < 2; ++i)
#pragma unroll
    for (int rg = 0; rg < 4; ++rg) {
      float rs = rsum[i][rg];
      rs += __shfl_xor(rs, 1);
      rs += __shfl_xor(rs, 2);
      rs += __shfl_xor(rs, 4);
      rs += __shfl_xor(rs, 8);
      rinv[i][rg] = __fdividef(1.0f, rs);
    }
#pragma unroll
  for (int i = 0; i < 2; ++i)
#pragma unroll
    for (int j = 0; j < 8; ++j)
#pragma unroll
      for (int rg = 0; rg < 4; ++rg) {
        int srow = n * 128 + wid * 32 + i * 16 + q4 * 4 + rg;
        int col = h * 128 + j * 16 + l16;
        attnout[((size_t)b * 8192 + srow) * 1024 + col] = f2bf(acco[i][j][rg] * rinv[i][rg]);
      }
}

// ---------------------------------------------------------------------------
extern "C" void kernel_launch(void* const* d_in, const int* in_sizes, int n_in,
                              void* d_out, int out_size, void* d_ws, size_t ws_size,
                              hipStream_t stream) {
  (void)in_sizes; (void)n_in; (void)out_size; (void)ws_size;
  const float* hs    = (const float*)d_in[0];
  const float* pemb  = (const float*)d_in[1];
  const float* Wq    = (const float*)d_in[2];
  const float* Wk    = (const float*)d_in[3];
  const float* Wv    = (const float*)d_in[4];
  const float* Wrel  = (const float*)d_in[5];
  const float* Wpost = (const float*)d_in[6];
  const float* pds   = (const float*)d_in[7];
  float* out = (float*)d_out;

  char* w = (char*)d_ws;
  auto alloc = [&](size_t bytes) -> char* {
    char* p = w; w += (bytes + 255) & ~(size_t)255; return p;
  };
  short* hs_bf   = (short*)alloc((size_t)16384 * 1024 * 2); // 33.5 MB (attnout aliases later)
  short* pos_bf  = (short*)alloc((size_t)384 * 1024 * 2);
  short* Wq_t    = (short*)alloc((size_t)1024 * 1024 * 2);
  short* Wk_t    = (short*)alloc((size_t)1024 * 1024 * 2);
  short* Wv_t    = (short*)alloc((size_t)1024 * 1024 * 2);
  short* Wrel_t  = (short*)alloc((size_t)1024 * 1024 * 2);
  short* Wpost_t = (short*)alloc((size_t)1024 * 1024 * 2);
  float* qsc     = (float*)alloc(512);
  short* q_bf    = (short*)alloc((size_t)2 * 64 * 8 * 128 * 128 * 2); // 33.5 MB
  short* kpad    = (short*)alloc((size_t)2 * 8 * 8448 * 128 * 2);     // 34.6 MB
  short* vpadT   = (short*)alloc((size_t)2 * 8 * 128 * 8448 * 2);     // 34.6 MB
  short* relk    = (short*)alloc((size_t)8 * 384 * 128 * 2);
  short* bds     = (short*)alloc((size_t)64 * 8 * 128 * 384 * 2);     // 50.3 MB, per-b (reused)
  short* attnout = hs_bf;  // hs_bf dead after V projection; attn starts after
  // total ~199 MB (< 232 MB known-good from R1)

  const float kscale = (float)(log1p(exp(1.0)) / log(2.0));
  const double qsb = (1.0 / sqrt(128.0)) / log(2.0);

  cvt_bf16_k<<<16384, 256, 0, stream>>>(hs, hs_bf, 16384 * 1024);
  cvt_bf16_k<<<384, 256, 0, stream>>>(pemb, pos_bf, 384 * 1024);
  dim3 tg(16, 16);
  wtrans_k<<<tg, 256, 0, stream>>>(Wq, Wq_t);
  wtrans_k<<<tg, 256, 0, stream>>>(Wk, Wk_t);
  wtrans_k<<<tg, 256, 0, stream>>>(Wv, Wv_t);
  wtrans_k<<<tg, 256, 0, stream>>>(Wrel, Wrel_t);
  wtrans_k<<<tg, 256, 0, stream>>>(Wpost, Wpost_t);
  qscale_k<<<1, 128, 0, stream>>>(pds, qsc, qsb);
  hipMemsetAsync(kpad, 0, (size_t)2 * 8 * 8448 * 128 * 2, stream);
  vpadzero_k<<<2048, 256, 0, stream>>>(vpadT);

  dim3 g128(128, 8);
  gemm_bt_k<0><<<g128, 256, 0, stream>>>(hs_bf, Wq_t, q_bf, nullptr, qsc, 0.f);
  gemm_bt_k<1><<<g128, 256, 0, stream>>>(hs_bf, Wk_t, kpad, nullptr, qsc, kscale);
  gemm_bt_k<2><<<g128, 256, 0, stream>>>(hs_bf, Wv_t, vpadT, nullptr, qsc, 0.f);
  gemm_bt_k<3><<<dim3(3, 8), 256, 0, stream>>>(pos_bf, Wrel_t, relk, nullptr, qsc, 0.f);

  for (int b = 0; b < 2; ++b) {
    const short* qb_b = q_bf + (size_t)b * 64 * 8 * 128 * 128;
    bd_gemm_k<<<dim3(3, 512), 256, 0, stream>>>(qb_b, relk, bds);
    attn_k<<<512, 256, 0, stream>>>(qb_b, kpad, vpadT, bds, attnout, b);
  }

  gemm_bt_k<4><<<g128, 256, 0, stream>>>(attnout, Wpost_t, nullptr, out, qsc, 0.f);
}

// Round 4
// 557.311 us; speedup vs baseline: 1.0294x; 1.0294x over previous
//
#include <hip/hip_runtime.h>
#include <cmath>

// ---------------------------------------------------------------------------
// Gemma4 audio attention, MI355X bf16-MFMA pipeline.
// B=2 S=8192 HID=1024 H=8 D=128 CHUNK=128 PAST=127 FUT=128 CTX=383 POS=384
// R4: (1) QKV fused into one XCD-pinned-swizzle GEMM (A read once per XCD);
//     (2) post GEMM same swizzle; (3) attn_k 4 barriers/tile w/ full P slab.
// Workspace ~199 MB (ws_size ceiling is between 232 and 283 MB).
// ---------------------------------------------------------------------------

using bf16x8 = __attribute__((ext_vector_type(8))) short;
using f32x4  = __attribute__((ext_vector_type(4))) float;
using s16x4  = __attribute__((ext_vector_type(4))) short;

__device__ __forceinline__ short f2bf(float f) {
  unsigned u = __float_as_uint(f);
  u = (u + 0x7FFF + ((u >> 16) & 1)) >> 16;   // RNE
  return (short)u;
}
__device__ __forceinline__ float bf2f(unsigned short s) {
  return __uint_as_float(((unsigned)s) << 16);
}

// async global->LDS, 16B per lane. LDS dest must be wave-uniform base + lane*16.
__device__ __forceinline__ void gl16(void* lds, const void* gptr) {
  __builtin_amdgcn_global_load_lds(
      (const __attribute__((address_space(1))) unsigned int*)gptr,
      (__attribute__((address_space(3))) unsigned int*)lds, 16, 0, 0);
}

// ---------------------------------------------------------------------------
// elementwise fp32 -> bf16
__global__ void cvt_bf16_k(const float* __restrict__ in, short* __restrict__ out, int n) {
  int i = (blockIdx.x * 256 + threadIdx.x) * 4;
  if (i + 3 < n) {
    float4 v = *(const float4*)&in[i];
    s16x4 o;
    o[0] = f2bf(v.x); o[1] = f2bf(v.y); o[2] = f2bf(v.z); o[3] = f2bf(v.w);
    *(s16x4*)&out[i] = o;
  }
}

// W (1024x1024 f32, [k][n]) -> Wt (bf16, [n][k])
__global__ void wtrans_k(const float* __restrict__ W, short* __restrict__ Wt) {
  __shared__ float T[64 * 65];
  const int tid = threadIdx.x;
  const int bx = blockIdx.x, by = blockIdx.y; // bx: n-tile, by: k-tile
#pragma unroll
  for (int it = 0; it < 4; ++it) {
    int ci = it * 256 + tid;
    int k = ci >> 4, n4 = (ci & 15) * 4;
    float4 v = *(const float4*)&W[(size_t)(by * 64 + k) * 1024 + bx * 64 + n4];
    T[k * 65 + n4 + 0] = v.x;
    T[k * 65 + n4 + 1] = v.y;
    T[k * 65 + n4 + 2] = v.z;
    T[k * 65 + n4 + 3] = v.w;
  }
  __syncthreads();
#pragma unroll
  for (int it = 0; it < 2; ++it) {
    int co = it * 256 + tid;
    int nn = co >> 3, k8 = (co & 7) * 8;
    bf16x8 o;
#pragma unroll
    for (int jj = 0; jj < 8; ++jj) o[jj] = f2bf(T[(k8 + jj) * 65 + nn]);
    *(bf16x8*)&Wt[(size_t)(bx * 64 + nn) * 1024 + by * 64 + k8] = o;
  }
}

// qscale[d] = (1/sqrt(128))/ln2 * softplus(pds[d])
__global__ void qscale_k(const float* __restrict__ pds, float* __restrict__ qs, double qsb) {
  int d = threadIdx.x;
  double x = (double)pds[d];
  qs[d] = (float)(qsb * log1p(exp(x)));
}

// zero vpadT pad columns: keys [0,127) and [8319,8448)
__global__ void vpadzero_k(short* __restrict__ vpadT) {
  int row = blockIdx.x;                 // (b*8+h)*128 + d   (2048 rows)
  int t = threadIdx.x;                  // 256
  int key = (t < 127) ? t : (8192 + t); // 0..126 and 8319..8447
  vpadT[(size_t)row * 8448 + key] = 0;
}

// ---------------------------------------------------------------------------
// Fused QKV GEMM, XCD-pinned swizzle. A: hs_bf [16384][1024]. Bt3: the three
// transposed weights contiguous as [3072][1024] (n-major, k-contig).
// 1-D grid 3072: xcd = id&7 owns m-tiles [xcd*16, xcd*16+16); within an XCD
// the 24 n-tiles of one m-tile run consecutively -> A-tile read once per XCD.
__global__ __launch_bounds__(256, 3)
void qkv_fused_k(const short* __restrict__ A, const short* __restrict__ Bt3,
                 short* __restrict__ q_bf, short* __restrict__ kpad,
                 short* __restrict__ vpadT,
                 const float* __restrict__ qsc, float kscale) {
  __shared__ __align__(16) short As[128 * 32];
  __shared__ __align__(16) short Bs[128 * 32];
  __shared__ __align__(16) short Tv[128 * 136];

  const int tid = threadIdx.x;
  const int lane = tid & 63, wid = tid >> 6;
  const int q4 = lane >> 4, l16 = lane & 15;
  const int wr = wid >> 1, wc = wid & 1;

  const int id = blockIdx.x;
  const int xcd = id & 7, local = id >> 3;     // local in [0,384)
  const int mm = local / 24, nn = local - mm * 24;
  const int m0 = (xcd * 16 + mm) * 128;        // row tile
  const int w = nn >> 3, nc = nn & 7;          // weight {0=Q,1=K,2=V}, col tile
  const short* Bt = Bt3 + ((size_t)w * 1024 + nc * 128) * 1024;

  const f32x4 z4 = {0.f, 0.f, 0.f, 0.f};
  f32x4 acc[4][4];
#pragma unroll
  for (int i = 0; i < 4; ++i)
#pragma unroll
    for (int j = 0; j < 4; ++j) acc[i][j] = z4;

  const int r0 = tid >> 2, s0_ = (tid & 3) * 8;

  for (int kk = 0; kk < 1024; kk += 32) {
    __syncthreads();
    gl16(&As[tid * 8],         A  + (size_t)(m0 + r0) * 1024 + kk + s0_);
    gl16(&Bs[tid * 8],         Bt + (size_t)r0 * 1024 + kk + s0_);
    gl16(&As[(256 + tid) * 8], A  + (size_t)(m0 + 64 + r0) * 1024 + kk + s0_);
    gl16(&Bs[(256 + tid) * 8], Bt + (size_t)(64 + r0) * 1024 + kk + s0_);
    __syncthreads();
    bf16x8 af[4], bfv[4];
#pragma unroll
    for (int i = 0; i < 4; ++i)
      af[i] = *(const bf16x8*)&As[(wr * 64 + i * 16 + l16) * 32 + q4 * 8];
#pragma unroll
    for (int j = 0; j < 4; ++j)
      bfv[j] = *(const bf16x8*)&Bs[(wc * 64 + j * 16 + l16) * 32 + q4 * 8];
#pragma unroll
    for (int i = 0; i < 4; ++i)
#pragma unroll
      for (int j = 0; j < 4; ++j)
        acc[i][j] = __builtin_amdgcn_mfma_f32_16x16x32_bf16(af[i], bfv[j], acc[i][j], 0, 0, 0);
  }

  float qsv[4];
  if (w == 0) {
#pragma unroll
    for (int j = 0; j < 4; ++j) qsv[j] = qsc[wc * 64 + j * 16 + l16];
  }

#pragma unroll
  for (int i = 0; i < 4; ++i) {
#pragma unroll
    for (int j = 0; j < 4; ++j) {
#pragma unroll
      for (int rg = 0; rg < 4; ++rg) {
        const int row = m0 + wr * 64 + i * 16 + q4 * 4 + rg;
        const int d = wc * 64 + j * 16 + l16;  // col within the 128-wide h-tile
        const int h = nc;
        const float v = acc[i][j][rg];
        if (w == 0) {              // Q -> q_bf[(b*64+n)*8+h][c][d] * qscale[d]
          int b = row >> 13, s = row & 8191;
          int n = s >> 7, c = s & 127;
          q_bf[((size_t)(((b * 64 + n) * 8 + h) * 128 + c)) * 128 + d] = f2bf(v * qsv[j]);
        } else if (w == 1) {       // K -> kpad[b][h][127+s][d] * kscale
          int b = row >> 13, s = row & 8191;
          kpad[((size_t)(b * 8 + h) * 8448 + 127 + s) * 128 + d] = f2bf(v * kscale);
        } else {                   // V -> LDS transpose tile
          int sl = wr * 64 + i * 16 + q4 * 4 + rg;
          Tv[d * 136 + sl] = f2bf(v);
        }
      }
    }
  }

  if (w == 2) {
    __syncthreads();
    const int b = m0 >> 13, ss = m0 & 8191, h = nc;
#pragma unroll
    for (int it = 0; it < 8; ++it) {
      int co = it * 256 + tid;
      int d = co >> 4, s8 = (co & 15) * 8;
      *(bf16x8*)&vpadT[((size_t)(b * 8 + h) * 128 + d) * 8448 + 127 + ss + s8] =
          *(const bf16x8*)&Tv[d * 136 + s8];
    }
  }
}

// ---------------------------------------------------------------------------
// Post GEMM (f32 out), same XCD-pinned swizzle. 1-D grid 1024.
__global__ __launch_bounds__(256, 3)
void post_gemm_k(const short* __restrict__ A, const short* __restrict__ Bt,
                 float* __restrict__ outf) {
  __shared__ __align__(16) short As[128 * 32];
  __shared__ __align__(16) short Bs[128 * 32];

  const int tid = threadIdx.x;
  const int lane = tid & 63, wid = tid >> 6;
  const int q4 = lane >> 4, l16 = lane & 15;
  const int wr = wid >> 1, wc = wid & 1;

  const int id = blockIdx.x;
  const int xcd = id & 7, local = id >> 3;     // local in [0,128)
  const int mm = local >> 3, nn = local & 7;
  const int m0 = (xcd * 16 + mm) * 128, n0 = nn * 128;

  const f32x4 z4 = {0.f, 0.f, 0.f, 0.f};
  f32x4 acc[4][4];
#pragma unroll
  for (int i = 0; i < 4; ++i)
#pragma unroll
    for (int j = 0; j < 4; ++j) acc[i][j] = z4;

  const int r0 = tid >> 2, s0_ = (tid & 3) * 8;

  for (int kk = 0; kk < 1024; kk += 32) {
    __syncthreads();
    gl16(&As[tid * 8],         A  + (size_t)(m0 + r0) * 1024 + kk + s0_);
    gl16(&Bs[tid * 8],         Bt + (size_t)(n0 + r0) * 1024 + kk + s0_);
    gl16(&As[(256 + tid) * 8], A  + (size_t)(m0 + 64 + r0) * 1024 + kk + s0_);
    gl16(&Bs[(256 + tid) * 8], Bt + (size_t)(n0 + 64 + r0) * 1024 + kk + s0_);
    __syncthreads();
    bf16x8 af[4], bfv[4];
#pragma unroll
    for (int i = 0; i < 4; ++i)
      af[i] = *(const bf16x8*)&As[(wr * 64 + i * 16 + l16) * 32 + q4 * 8];
#pragma unroll
    for (int j = 0; j < 4; ++j)
      bfv[j] = *(const bf16x8*)&Bs[(wc * 64 + j * 16 + l16) * 32 + q4 * 8];
#pragma unroll
    for (int i = 0; i < 4; ++i)
#pragma unroll
      for (int j = 0; j < 4; ++j)
        acc[i][j] = __builtin_amdgcn_mfma_f32_16x16x32_bf16(af[i], bfv[j], acc[i][j], 0, 0, 0);
  }

#pragma unroll
  for (int i = 0; i < 4; ++i)
#pragma unroll
    for (int j = 0; j < 4; ++j)
#pragma unroll
      for (int rg = 0; rg < 4; ++rg) {
        const int row = m0 + wr * 64 + i * 16 + q4 * 4 + rg;
        const int col = n0 + wc * 64 + j * 16 + l16;
        outf[(size_t)row * 1024 + col] = acc[i][j][rg];
      }
}

// ---------------------------------------------------------------------------
// REL GEMM: C = pos_bf(384x1024) @ Wrel_t^T -> relk[h][p][d]. grid (3,8).
__global__ __launch_bounds__(256, 2)
void rel_gemm_k(const short* __restrict__ A, const short* __restrict__ Bt,
                short* __restrict__ relk) {
  __shared__ __align__(16) short As[128 * 32];
  __shared__ __align__(16) short Bs[128 * 32];

  const int tid = threadIdx.x;
  const int lane = tid & 63, wid = tid >> 6;
  const int q4 = lane >> 4, l16 = lane & 15;
  const int wr = wid >> 1, wc = wid & 1;
  const int m0 = blockIdx.x * 128, n0 = blockIdx.y * 128;

  const f32x4 z4 = {0.f, 0.f, 0.f, 0.f};
  f32x4 acc[4][4];
#pragma unroll
  for (int i = 0; i < 4; ++i)
#pragma unroll
    for (int j = 0; j < 4; ++j) acc[i][j] = z4;

  const int r0 = tid >> 2, s0_ = (tid & 3) * 8;
  for (int kk = 0; kk < 1024; kk += 32) {
    __syncthreads();
    gl16(&As[tid * 8],         A  + (size_t)(m0 + r0) * 1024 + kk + s0_);
    gl16(&Bs[tid * 8],         Bt + (size_t)(n0 + r0) * 1024 + kk + s0_);
    gl16(&As[(256 + tid) * 8], A  + (size_t)(m0 + 64 + r0) * 1024 + kk + s0_);
    gl16(&Bs[(256 + tid) * 8], Bt + (size_t)(n0 + 64 + r0) * 1024 + kk + s0_);
    __syncthreads();
    bf16x8 af[4], bfv[4];
#pragma unroll
    for (int i = 0; i < 4; ++i)
      af[i] = *(const bf16x8*)&As[(wr * 64 + i * 16 + l16) * 32 + q4 * 8];
#pragma unroll
    for (int j = 0; j < 4; ++j)
      bfv[j] = *(const bf16x8*)&Bs[(wc * 64 + j * 16 + l16) * 32 + q4 * 8];
#pragma unroll
    for (int i = 0; i < 4; ++i)
#pragma unroll
      for (int j = 0; j < 4; ++j)
        acc[i][j] = __builtin_amdgcn_mfma_f32_16x16x32_bf16(af[i], bfv[j], acc[i][j], 0, 0, 0);
  }

#pragma unroll
  for (int i = 0; i < 4; ++i)
#pragma unroll
    for (int j = 0; j < 4; ++j)
#pragma unroll
      for (int rg = 0; rg < 4; ++rg) {
        const int row = m0 + wr * 64 + i * 16 + q4 * 4 + rg;
        const int col = n0 + wc * 64 + j * 16 + l16;
        int h = col >> 7, d = col & 127;
        relk[(size_t)(h * 384 + row) * 128 + d] = f2bf(acc[i][j][rg]);
      }
}

// ---------------------------------------------------------------------------
// bdo = q_tile(128x128) @ relk[h](384x128)^T, rel-shift applied in epilogue,
// stored in MFMA-fragment order for attn_k.
__global__ __launch_bounds__(256, 2)
void bd_gemm_k(const short* __restrict__ qb_b, const short* __restrict__ relk,
               short* __restrict__ bds) {
  __shared__ __align__(16) short As[128 * 32];
  __shared__ __align__(16) short Bs[128 * 32];
  const int tid = threadIdx.x;
  const int lane = tid & 63, wid = tid >> 6;
  const int q4 = lane >> 4, l16 = lane & 15;
  const int wr = wid >> 1, wc = wid & 1;
  const int p0 = blockIdx.x * 128;
  const int nh = blockIdx.y;          // n*8 + h  (within b)
  const int h = nh & 7;
  const short* A = qb_b + (size_t)nh * 16384;
  const short* Bt = relk + (size_t)h * (384 * 128);
  short* bdo = bds + (size_t)nh * 49152;

  const f32x4 z4 = {0.f, 0.f, 0.f, 0.f};
  f32x4 acc[4][4];
#pragma unroll
  for (int i = 0; i < 4; ++i)
#pragma unroll
    for (int j = 0; j < 4; ++j) acc[i][j] = z4;

  const int r0 = tid >> 2, s0_ = (tid & 3) * 8;
  for (int kk = 0; kk < 128; kk += 32) {
    __syncthreads();
    gl16(&As[tid * 8],         A  + (size_t)r0 * 128 + kk + s0_);
    gl16(&Bs[tid * 8],         Bt + (size_t)(p0 + r0) * 128 + kk + s0_);
    gl16(&As[(256 + tid) * 8], A  + (size_t)(64 + r0) * 128 + kk + s0_);
    gl16(&Bs[(256 + tid) * 8], Bt + (size_t)(p0 + 64 + r0) * 128 + kk + s0_);
    __syncthreads();
    bf16x8 af[4], bfv[4];
#pragma unroll
    for (int i = 0; i < 4; ++i)
      af[i] = *(const bf16x8*)&As[(wr * 64 + i * 16 + l16) * 32 + q4 * 8];
#pragma unroll
    for (int j = 0; j < 4; ++j)
      bfv[j] = *(const bf16x8*)&Bs[(wc * 64 + j * 16 + l16) * 32 + q4 * 8];
#pragma unroll
    for (int i = 0; i < 4; ++i)
#pragma unroll
      for (int j = 0; j < 4; ++j)
        acc[i][j] = __builtin_amdgcn_mfma_f32_16x16x32_bf16(af[i], bfv[j], acc[i][j], 0, 0, 0);
  }

  // rel-shift: (r,p) -> (c,k): flat r*384+p == c*383+k, drop c >= 128
#pragma unroll
  for (int i = 0; i < 4; ++i)
#pragma unroll
    for (int j = 0; j < 4; ++j)
#pragma unroll
      for (int rg = 0; rg < 4; ++rg) {
        int r = wr * 64 + i * 16 + q4 * 4 + rg;
        int p = p0 + wc * 64 + j * 16 + l16;
        int t = r + p;
        int c = (t < 383) ? r : (r + 1);
        int k = (t < 383) ? t : (t - 383);
        if (c < 128) {
          int tt = k >> 7, jj = (k >> 4) & 7, ll = k & 15;
          int wa = c >> 5, ia = (c >> 4) & 1, qa = (c >> 2) & 3, ra = c & 3;
          bdo[((((size_t)tt * 8 + jj) * 256) + wa * 64 + qa * 16 + ll) * 8 + ia * 4 + ra] =
              f2bf(acc[i][j][rg]);
        }
      }
}

// ---------------------------------------------------------------------------
// fused local attention: one WG per (n,h) for fixed b. 4 barriers per key-tile.
__global__ __launch_bounds__(256, 2)
void attn_k(const short* __restrict__ qb_b, const short* __restrict__ kpad,
            const short* __restrict__ vpadT, const short* __restrict__ bds,
            short* __restrict__ attnout, int b) {
  __shared__ __align__(16) short Ks[4 * 128 * 32]; // slabs [dc][row][32], reused Q->K->V
  __shared__ __align__(16) short Ps[128 * 136];    // full P tile, padded stride

  const int tid = threadIdx.x;
  const int lane = tid & 63, wid = tid >> 6;
  const int q4 = lane >> 4, l16 = lane & 15;
  const int bx = blockIdx.x;          // n*8 + h
  const int n = bx >> 3, h = bx & 7;

  const short* qtile = qb_b + (size_t)bx * 16384;
  const short* kbase = kpad + ((size_t)(b * 8 + h) * 8448 + n * 128) * 128;
  const short* vtb = vpadT + (size_t)(b * 8 + h) * 128 * 8448 + n * 128;
  const short* bdb = bds + (size_t)bx * 49152;

  // stage Q into Ks slabs, pull fragments to registers
#pragma unroll
  for (int it = 0; it < 8; ++it) {
    int ci = it * 256 + tid;
    int dc = ci >> 9, rr = (ci >> 2) & 127, sub = (ci & 3) * 8;
    gl16(&Ks[ci * 8], qtile + rr * 128 + dc * 32 + sub);
  }
  __syncthreads();
  bf16x8 qf[2][4];
#pragma unroll
  for (int i = 0; i < 2; ++i)
#pragma unroll
    for (int dc = 0; dc < 4; ++dc)
      qf[i][dc] = *(const bf16x8*)&Ks[dc * 4096 + (wid * 32 + i * 16 + l16) * 32 + q4 * 8];

  const f32x4 z4 = {0.f, 0.f, 0.f, 0.f};
  f32x4 acco[2][8];
#pragma unroll
  for (int i = 0; i < 2; ++i)
#pragma unroll
    for (int j = 0; j < 8; ++j) acco[i][j] = z4;
  float rsum[2][4] = {};

  for (int t = 0; t < 3; ++t) {
    __syncthreads();  // (A) Ks/Ps free from previous iteration's PV
#pragma unroll
    for (int it = 0; it < 8; ++it) {  // stage K tile
      int ci = it * 256 + tid;
      int dc = ci >> 9, rr = (ci >> 2) & 127, sub = (ci & 3) * 8;
      gl16(&Ks[ci * 8], kbase + (size_t)(t * 128 + rr) * 128 + dc * 32 + sub);
    }

    // coalesced bd fragment loads for this t (overlap with K staging wait)
    bf16x8 bdv[8];
#pragma unroll
    for (int j = 0; j < 8; ++j)
      bdv[j] = *(const bf16x8*)&bdb[(((size_t)t * 8 + j) * 256 + wid * 64 + lane) * 8];

    __syncthreads();  // (B) K ready

    // S = Q @ K^T
    f32x4 accs[2][8];
#pragma unroll
    for (int i = 0; i < 2; ++i)
#pragma unroll
      for (int j = 0; j < 8; ++j) accs[i][j] = z4;
#pragma unroll
    for (int dc = 0; dc < 4; ++dc) {
      bf16x8 kf[8];
#pragma unroll
      for (int j = 0; j < 8; ++j)
        kf[j] = *(const bf16x8*)&Ks[dc * 4096 + (j * 16 + l16) * 32 + q4 * 8];
#pragma unroll
      for (int i = 0; i < 2; ++i)
#pragma unroll
        for (int j = 0; j < 8; ++j)
          accs[i][j] = __builtin_amdgcn_mfma_f32_16x16x32_bf16(qf[i][dc], kf[j], accs[i][j], 0, 0, 0);
    }

    // logits: s = ac + bd;  w = exp2(-100*log2e / (exp2(s*2*log2e/50) + 1))
#pragma unroll
    for (int i = 0; i < 2; ++i) {
#pragma unroll
      for (int j = 0; j < 8; ++j) {
        const int kg = t * 128 + j * 16 + l16;
#pragma unroll
        for (int rg = 0; rg < 4; ++rg) {
          float sv = accs[i][j][rg] + bf2f((unsigned short)bdv[j][i * 4 + rg]);
          float tt = exp2f(sv * 0.057707801635558534f);
          float wgt = exp2f(-144.26950408889634f * __fdividef(1.0f, tt + 1.0f));
          wgt = (kg < 383) ? wgt : 0.0f;
          accs[i][j][rg] = wgt;
          rsum[i][rg] += wgt;
        }
      }
    }
    __syncthreads();  // (C) all waves done reading Ks (K tile)

    // stage V^T tile into Ks slabs [kc][d][32keys]; write full P to Ps
#pragma unroll
    for (int it = 0; it < 8; ++it) {
      int ci = it * 256 + tid;
      int kc = ci >> 9, dd = (ci >> 2) & 127, sub = (ci & 3) * 8;
      gl16(&Ks[ci * 8], vtb + (size_t)dd * 8448 + t * 128 + kc * 32 + sub);
    }
#pragma unroll
    for (int i = 0; i < 2; ++i)
#pragma unroll
      for (int j = 0; j < 8; ++j)
#pragma unroll
        for (int rg = 0; rg < 4; ++rg) {
          int c = wid * 32 + i * 16 + q4 * 4 + rg;
          int kl = j * 16 + l16;
          Ps[c * 136 + kl] = f2bf(accs[i][j][rg]);
        }
    __syncthreads();  // (D) V + P ready

    // PV over kc = 0..3 in one burst
#pragma unroll
    for (int kc = 0; kc < 4; ++kc) {
      bf16x8 pf[2], vf[8];
#pragma unroll
      for (int i = 0; i < 2; ++i)
        pf[i] = *(const bf16x8*)&Ps[(wid * 32 + i * 16 + l16) * 136 + kc * 32 + q4 * 8];
#pragma unroll
      for (int j = 0; j < 8; ++j)
        vf[j] = *(const bf16x8*)&Ks[kc * 4096 + (j * 16 + l16) * 32 + q4 * 8];
#pragma unroll
      for (int i = 0; i < 2; ++i)
#pragma unroll
        for (int j = 0; j < 8; ++j)
          acco[i][j] = __builtin_amdgcn_mfma_f32_16x16x32_bf16(pf[i], vf[j], acco[i][j], 0, 0, 0);
    }
  }

  // row-sum butterfly over the 16-lane group (cols), normalize, write bf16
  float rinv[2][4];
#pragma unroll
  for (int i = 0; i < 2; ++i)
#pragma unroll
    for (int rg = 0; rg < 4; ++rg) {
      float rs = rsum[i][rg];
      rs += __shfl_xor(rs, 1);
      rs += __shfl_xor(rs, 2);
      rs += __shfl_xor(rs, 4);
      rs += __shfl_xor(rs, 8);
      rinv[i][rg] = __fdividef(1.0f, rs);
    }
#pragma unroll
  for (int i = 0; i < 2; ++i)
#pragma unroll
    for (int j = 0; j < 8; ++j)
#pragma unroll
      for (int rg = 0; rg < 4; ++rg) {
        int srow = n * 128 + wid * 32 + i * 16 + q4 * 4 + rg;
        int col = h * 128 + j * 16 + l16;
        attnout[((size_t)b * 8192 + srow) * 1024 + col] = f2bf(acco[i][j][rg] * rinv[i][rg]);
      }
}

// ---------------------------------------------------------------------------
extern "C" void kernel_launch(void* const* d_in, const int* in_sizes, int n_in,
                              void* d_out, int out_size, void* d_ws, size_t ws_size,
                              hipStream_t stream) {
  (void)in_sizes; (void)n_in; (void)out_size; (void)ws_size;
  const float* hs    = (const float*)d_in[0];
  const float* pemb  = (const float*)d_in[1];
  const float* Wq    = (const float*)d_in[2];
  const float* Wk    = (const float*)d_in[3];
  const float* Wv    = (const float*)d_in[4];
  const float* Wrel  = (const float*)d_in[5];
  const float* Wpost = (const float*)d_in[6];
  const float* pds   = (const float*)d_in[7];
  float* out = (float*)d_out;

  char* w = (char*)d_ws;
  auto alloc = [&](size_t bytes) -> char* {
    char* p = w; w += (bytes + 255) & ~(size_t)255; return p;
  };
  short* hs_bf   = (short*)alloc((size_t)16384 * 1024 * 2); // 33.5 MB (attnout aliases later)
  short* pos_bf  = (short*)alloc((size_t)384 * 1024 * 2);
  short* Wq_t    = (short*)alloc((size_t)1024 * 1024 * 2);  // Wq_t/Wk_t/Wv_t contiguous = Bt3
  short* Wk_t    = (short*)alloc((size_t)1024 * 1024 * 2);
  short* Wv_t    = (short*)alloc((size_t)1024 * 1024 * 2);
  short* Wrel_t  = (short*)alloc((size_t)1024 * 1024 * 2);
  short* Wpost_t = (short*)alloc((size_t)1024 * 1024 * 2);
  float* qsc     = (float*)alloc(512);
  short* q_bf    = (short*)alloc((size_t)2 * 64 * 8 * 128 * 128 * 2); // 33.5 MB
  short* kpad    = (short*)alloc((size_t)2 * 8 * 8448 * 128 * 2);     // 34.6 MB
  short* vpadT   = (short*)alloc((size_t)2 * 8 * 128 * 8448 * 2);     // 34.6 MB
  short* relk    = (short*)alloc((size_t)8 * 384 * 128 * 2);
  short* bds     = (short*)alloc((size_t)64 * 8 * 128 * 384 * 2);     // 50.3 MB, per-b (reused)
  short* attnout = hs_bf;  // hs_bf dead after QKV projection; attn starts after
  // total ~199 MB (< 232 MB known-good)

  const float kscale = (float)(log1p(exp(1.0)) / log(2.0));
  const double qsb = (1.0 / sqrt(128.0)) / log(2.0);

  cvt_bf16_k<<<16384, 256, 0, stream>>>(hs, hs_bf, 16384 * 1024);
  cvt_bf16_k<<<384, 256, 0, stream>>>(pemb, pos_bf, 384 * 1024);
  dim3 tg(16, 16);
  wtrans_k<<<tg, 256, 0, stream>>>(Wq, Wq_t);
  wtrans_k<<<tg, 256, 0, stream>>>(Wk, Wk_t);
  wtrans_k<<<tg, 256, 0, stream>>>(Wv, Wv_t);
  wtrans_k<<<tg, 256, 0, stream>>>(Wrel, Wrel_t);
  wtrans_k<<<tg, 256, 0, stream>>>(Wpost, Wpost_t);
  qscale_k<<<1, 128, 0, stream>>>(pds, qsc, qsb);
  hipMemsetAsync(kpad, 0, (size_t)2 * 8 * 8448 * 128 * 2, stream);
  vpadzero_k<<<2048, 256, 0, stream>>>(vpadT);

  qkv_fused_k<<<3072, 256, 0, stream>>>(hs_bf, Wq_t, q_bf, kpad, vpadT, qsc, kscale);
  rel_gemm_k<<<dim3(3, 8), 256, 0, stream>>>(pos_bf, Wrel_t, relk);

  for (int b = 0; b < 2; ++b) {
    const short* qb_b = q_bf + (size_t)b * 64 * 8 * 128 * 128;
    bd_gemm_k<<<dim3(3, 512), 256, 0, stream>>>(qb_b, relk, bds);
    attn_k<<<512, 256, 0, stream>>>(qb_b, kpad, vpadT, bds, attnout, b);
  }

  post_gemm_k<<<1024, 256, 0, stream>>>(attnout, Wpost_t, out);
}

// Round 5
// 550.210 us; speedup vs baseline: 1.0426x; 1.0129x over previous
//
#include <hip/hip_runtime.h>
#include <cmath>

// ---------------------------------------------------------------------------
// Gemma4 audio attention, MI355X bf16-MFMA pipeline.
// B=2 S=8192 HID=1024 H=8 D=128 CHUNK=128 PAST=127 FUT=128 CTX=383 POS=384
// R5: attn_k split into 64-query-row blocks (grid 1024/b, LDS 50.2 KB,
//     3 blocks/CU) to attack the barrier-latency bound. qkv/bd/rel/post
//     unchanged from R4. Workspace ~199 MB.
// ---------------------------------------------------------------------------

using bf16x8 = __attribute__((ext_vector_type(8))) short;
using f32x4  = __attribute__((ext_vector_type(4))) float;
using s16x4  = __attribute__((ext_vector_type(4))) short;

__device__ __forceinline__ short f2bf(float f) {
  unsigned u = __float_as_uint(f);
  u = (u + 0x7FFF + ((u >> 16) & 1)) >> 16;   // RNE
  return (short)u;
}
__device__ __forceinline__ float bf2f(unsigned short s) {
  return __uint_as_float(((unsigned)s) << 16);
}

// async global->LDS, 16B per lane. LDS dest must be wave-uniform base + lane*16.
__device__ __forceinline__ void gl16(void* lds, const void* gptr) {
  __builtin_amdgcn_global_load_lds(
      (const __attribute__((address_space(1))) unsigned int*)gptr,
      (__attribute__((address_space(3))) unsigned int*)lds, 16, 0, 0);
}

// ---------------------------------------------------------------------------
// elementwise fp32 -> bf16
__global__ void cvt_bf16_k(const float* __restrict__ in, short* __restrict__ out, int n) {
  int i = (blockIdx.x * 256 + threadIdx.x) * 4;
  if (i + 3 < n) {
    float4 v = *(const float4*)&in[i];
    s16x4 o;
    o[0] = f2bf(v.x); o[1] = f2bf(v.y); o[2] = f2bf(v.z); o[3] = f2bf(v.w);
    *(s16x4*)&out[i] = o;
  }
}

// W (1024x1024 f32, [k][n]) -> Wt (bf16, [n][k])
__global__ void wtrans_k(const float* __restrict__ W, short* __restrict__ Wt) {
  __shared__ float T[64 * 65];
  const int tid = threadIdx.x;
  const int bx = blockIdx.x, by = blockIdx.y; // bx: n-tile, by: k-tile
#pragma unroll
  for (int it = 0; it < 4; ++it) {
    int ci = it * 256 + tid;
    int k = ci >> 4, n4 = (ci & 15) * 4;
    float4 v = *(const float4*)&W[(size_t)(by * 64 + k) * 1024 + bx * 64 + n4];
    T[k * 65 + n4 + 0] = v.x;
    T[k * 65 + n4 + 1] = v.y;
    T[k * 65 + n4 + 2] = v.z;
    T[k * 65 + n4 + 3] = v.w;
  }
  __syncthreads();
#pragma unroll
  for (int it = 0; it < 2; ++it) {
    int co = it * 256 + tid;
    int nn = co >> 3, k8 = (co & 7) * 8;
    bf16x8 o;
#pragma unroll
    for (int jj = 0; jj < 8; ++jj) o[jj] = f2bf(T[(k8 + jj) * 65 + nn]);
    *(bf16x8*)&Wt[(size_t)(bx * 64 + nn) * 1024 + by * 64 + k8] = o;
  }
}

// qscale[d] = (1/sqrt(128))/ln2 * softplus(pds[d])
__global__ void qscale_k(const float* __restrict__ pds, float* __restrict__ qs, double qsb) {
  int d = threadIdx.x;
  double x = (double)pds[d];
  qs[d] = (float)(qsb * log1p(exp(x)));
}

// zero vpadT pad columns: keys [0,127) and [8319,8448)
__global__ void vpadzero_k(short* __restrict__ vpadT) {
  int row = blockIdx.x;                 // (b*8+h)*128 + d   (2048 rows)
  int t = threadIdx.x;                  // 256
  int key = (t < 127) ? t : (8192 + t); // 0..126 and 8319..8447
  vpadT[(size_t)row * 8448 + key] = 0;
}

// ---------------------------------------------------------------------------
// Fused QKV GEMM, XCD-pinned swizzle (unchanged from R4).
__global__ __launch_bounds__(256, 3)
void qkv_fused_k(const short* __restrict__ A, const short* __restrict__ Bt3,
                 short* __restrict__ q_bf, short* __restrict__ kpad,
                 short* __restrict__ vpadT,
                 const float* __restrict__ qsc, float kscale) {
  __shared__ __align__(16) short As[128 * 32];
  __shared__ __align__(16) short Bs[128 * 32];
  __shared__ __align__(16) short Tv[128 * 136];

  const int tid = threadIdx.x;
  const int lane = tid & 63, wid = tid >> 6;
  const int q4 = lane >> 4, l16 = lane & 15;
  const int wr = wid >> 1, wc = wid & 1;

  const int id = blockIdx.x;
  const int xcd = id & 7, local = id >> 3;     // local in [0,384)
  const int mm = local / 24, nn = local - mm * 24;
  const int m0 = (xcd * 16 + mm) * 128;        // row tile
  const int w = nn >> 3, nc = nn & 7;          // weight {0=Q,1=K,2=V}, col tile
  const short* Bt = Bt3 + ((size_t)w * 1024 + nc * 128) * 1024;

  const f32x4 z4 = {0.f, 0.f, 0.f, 0.f};
  f32x4 acc[4][4];
#pragma unroll
  for (int i = 0; i < 4; ++i)
#pragma unroll
    for (int j = 0; j < 4; ++j) acc[i][j] = z4;

  const int r0 = tid >> 2, s0_ = (tid & 3) * 8;

  for (int kk = 0; kk < 1024; kk += 32) {
    __syncthreads();
    gl16(&As[tid * 8],         A  + (size_t)(m0 + r0) * 1024 + kk + s0_);
    gl16(&Bs[tid * 8],         Bt + (size_t)r0 * 1024 + kk + s0_);
    gl16(&As[(256 + tid) * 8], A  + (size_t)(m0 + 64 + r0) * 1024 + kk + s0_);
    gl16(&Bs[(256 + tid) * 8], Bt + (size_t)(64 + r0) * 1024 + kk + s0_);
    __syncthreads();
    bf16x8 af[4], bfv[4];
#pragma unroll
    for (int i = 0; i < 4; ++i)
      af[i] = *(const bf16x8*)&As[(wr * 64 + i * 16 + l16) * 32 + q4 * 8];
#pragma unroll
    for (int j = 0; j < 4; ++j)
      bfv[j] = *(const bf16x8*)&Bs[(wc * 64 + j * 16 + l16) * 32 + q4 * 8];
#pragma unroll
    for (int i = 0; i < 4; ++i)
#pragma unroll
      for (int j = 0; j < 4; ++j)
        acc[i][j] = __builtin_amdgcn_mfma_f32_16x16x32_bf16(af[i], bfv[j], acc[i][j], 0, 0, 0);
  }

  float qsv[4];
  if (w == 0) {
#pragma unroll
    for (int j = 0; j < 4; ++j) qsv[j] = qsc[wc * 64 + j * 16 + l16];
  }

#pragma unroll
  for (int i = 0; i < 4; ++i) {
#pragma unroll
    for (int j = 0; j < 4; ++j) {
#pragma unroll
      for (int rg = 0; rg < 4; ++rg) {
        const int row = m0 + wr * 64 + i * 16 + q4 * 4 + rg;
        const int d = wc * 64 + j * 16 + l16;  // col within the 128-wide h-tile
        const int h = nc;
        const float v = acc[i][j][rg];
        if (w == 0) {              // Q -> q_bf[(b*64+n)*8+h][c][d] * qscale[d]
          int b = row >> 13, s = row & 8191;
          int n = s >> 7, c = s & 127;
          q_bf[((size_t)(((b * 64 + n) * 8 + h) * 128 + c)) * 128 + d] = f2bf(v * qsv[j]);
        } else if (w == 1) {       // K -> kpad[b][h][127+s][d] * kscale
          int b = row >> 13, s = row & 8191;
          kpad[((size_t)(b * 8 + h) * 8448 + 127 + s) * 128 + d] = f2bf(v * kscale);
        } else {                   // V -> LDS transpose tile
          int sl = wr * 64 + i * 16 + q4 * 4 + rg;
          Tv[d * 136 + sl] = f2bf(v);
        }
      }
    }
  }

  if (w == 2) {
    __syncthreads();
    const int b = m0 >> 13, ss = m0 & 8191, h = nc;
#pragma unroll
    for (int it = 0; it < 8; ++it) {
      int co = it * 256 + tid;
      int d = co >> 4, s8 = (co & 15) * 8;
      *(bf16x8*)&vpadT[((size_t)(b * 8 + h) * 128 + d) * 8448 + 127 + ss + s8] =
          *(const bf16x8*)&Tv[d * 136 + s8];
    }
  }
}

// ---------------------------------------------------------------------------
// Post GEMM (f32 out), XCD-pinned swizzle (unchanged).
__global__ __launch_bounds__(256, 3)
void post_gemm_k(const short* __restrict__ A, const short* __restrict__ Bt,
                 float* __restrict__ outf) {
  __shared__ __align__(16) short As[128 * 32];
  __shared__ __align__(16) short Bs[128 * 32];

  const int tid = threadIdx.x;
  const int lane = tid & 63, wid = tid >> 6;
  const int q4 = lane >> 4, l16 = lane & 15;
  const int wr = wid >> 1, wc = wid & 1;

  const int id = blockIdx.x;
  const int xcd = id & 7, local = id >> 3;     // local in [0,128)
  const int mm = local >> 3, nn = local & 7;
  const int m0 = (xcd * 16 + mm) * 128, n0 = nn * 128;

  const f32x4 z4 = {0.f, 0.f, 0.f, 0.f};
  f32x4 acc[4][4];
#pragma unroll
  for (int i = 0; i < 4; ++i)
#pragma unroll
    for (int j = 0; j < 4; ++j) acc[i][j] = z4;

  const int r0 = tid >> 2, s0_ = (tid & 3) * 8;

  for (int kk = 0; kk < 1024; kk += 32) {
    __syncthreads();
    gl16(&As[tid * 8],         A  + (size_t)(m0 + r0) * 1024 + kk + s0_);
    gl16(&Bs[tid * 8],         Bt + (size_t)(n0 + r0) * 1024 + kk + s0_);
    gl16(&As[(256 + tid) * 8], A  + (size_t)(m0 + 64 + r0) * 1024 + kk + s0_);
    gl16(&Bs[(256 + tid) * 8], Bt + (size_t)(n0 + 64 + r0) * 1024 + kk + s0_);
    __syncthreads();
    bf16x8 af[4], bfv[4];
#pragma unroll
    for (int i = 0; i < 4; ++i)
      af[i] = *(const bf16x8*)&As[(wr * 64 + i * 16 + l16) * 32 + q4 * 8];
#pragma unroll
    for (int j = 0; j < 4; ++j)
      bfv[j] = *(const bf16x8*)&Bs[(wc * 64 + j * 16 + l16) * 32 + q4 * 8];
#pragma unroll
    for (int i = 0; i < 4; ++i)
#pragma unroll
      for (int j = 0; j < 4; ++j)
        acc[i][j] = __builtin_amdgcn_mfma_f32_16x16x32_bf16(af[i], bfv[j], acc[i][j], 0, 0, 0);
  }

#pragma unroll
  for (int i = 0; i < 4; ++i)
#pragma unroll
    for (int j = 0; j < 4; ++j)
#pragma unroll
      for (int rg = 0; rg < 4; ++rg) {
        const int row = m0 + wr * 64 + i * 16 + q4 * 4 + rg;
        const int col = n0 + wc * 64 + j * 16 + l16;
        outf[(size_t)row * 1024 + col] = acc[i][j][rg];
      }
}

// ---------------------------------------------------------------------------
// REL GEMM: C = pos_bf(384x1024) @ Wrel_t^T -> relk[h][p][d]. grid (3,8).
__global__ __launch_bounds__(256, 2)
void rel_gemm_k(const short* __restrict__ A, const short* __restrict__ Bt,
                short* __restrict__ relk) {
  __shared__ __align__(16) short As[128 * 32];
  __shared__ __align__(16) short Bs[128 * 32];

  const int tid = threadIdx.x;
  const int lane = tid & 63, wid = tid >> 6;
  const int q4 = lane >> 4, l16 = lane & 15;
  const int wr = wid >> 1, wc = wid & 1;
  const int m0 = blockIdx.x * 128, n0 = blockIdx.y * 128;

  const f32x4 z4 = {0.f, 0.f, 0.f, 0.f};
  f32x4 acc[4][4];
#pragma unroll
  for (int i = 0; i < 4; ++i)
#pragma unroll
    for (int j = 0; j < 4; ++j) acc[i][j] = z4;

  const int r0 = tid >> 2, s0_ = (tid & 3) * 8;
  for (int kk = 0; kk < 1024; kk += 32) {
    __syncthreads();
    gl16(&As[tid * 8],         A  + (size_t)(m0 + r0) * 1024 + kk + s0_);
    gl16(&Bs[tid * 8],         Bt + (size_t)(n0 + r0) * 1024 + kk + s0_);
    gl16(&As[(256 + tid) * 8], A  + (size_t)(m0 + 64 + r0) * 1024 + kk + s0_);
    gl16(&Bs[(256 + tid) * 8], Bt + (size_t)(n0 + 64 + r0) * 1024 + kk + s0_);
    __syncthreads();
    bf16x8 af[4], bfv[4];
#pragma unroll
    for (int i = 0; i < 4; ++i)
      af[i] = *(const bf16x8*)&As[(wr * 64 + i * 16 + l16) * 32 + q4 * 8];
#pragma unroll
    for (int j = 0; j < 4; ++j)
      bfv[j] = *(const bf16x8*)&Bs[(wc * 64 + j * 16 + l16) * 32 + q4 * 8];
#pragma unroll
    for (int i = 0; i < 4; ++i)
#pragma unroll
      for (int j = 0; j < 4; ++j)
        acc[i][j] = __builtin_amdgcn_mfma_f32_16x16x32_bf16(af[i], bfv[j], acc[i][j], 0, 0, 0);
  }

#pragma unroll
  for (int i = 0; i < 4; ++i)
#pragma unroll
    for (int j = 0; j < 4; ++j)
#pragma unroll
      for (int rg = 0; rg < 4; ++rg) {
        const int row = m0 + wr * 64 + i * 16 + q4 * 4 + rg;
        const int col = n0 + wc * 64 + j * 16 + l16;
        int h = col >> 7, d = col & 127;
        relk[(size_t)(h * 384 + row) * 128 + d] = f2bf(acc[i][j][rg]);
      }
}

// ---------------------------------------------------------------------------
// bdo = q_tile(128x128) @ relk[h](384x128)^T, rel-shift applied in epilogue,
// stored in MFMA-fragment order for attn_k (unchanged from R4).
__global__ __launch_bounds__(256, 2)
void bd_gemm_k(const short* __restrict__ qb_b, const short* __restrict__ relk,
               short* __restrict__ bds) {
  __shared__ __align__(16) short As[128 * 32];
  __shared__ __align__(16) short Bs[128 * 32];
  const int tid = threadIdx.x;
  const int lane = tid & 63, wid = tid >> 6;
  const int q4 = lane >> 4, l16 = lane & 15;
  const int wr = wid >> 1, wc = wid & 1;
  const int p0 = blockIdx.x * 128;
  const int nh = blockIdx.y;          // n*8 + h  (within b)
  const int h = nh & 7;
  const short* A = qb_b + (size_t)nh * 16384;
  const short* Bt = relk + (size_t)h * (384 * 128);
  short* bdo = bds + (size_t)nh * 49152;

  const f32x4 z4 = {0.f, 0.f, 0.f, 0.f};
  f32x4 acc[4][4];
#pragma unroll
  for (int i = 0; i < 4; ++i)
#pragma unroll
    for (int j = 0; j < 4; ++j) acc[i][j] = z4;

  const int r0 = tid >> 2, s0_ = (tid & 3) * 8;
  for (int kk = 0; kk < 128; kk += 32) {
    __syncthreads();
    gl16(&As[tid * 8],         A  + (size_t)r0 * 128 + kk + s0_);
    gl16(&Bs[tid * 8],         Bt + (size_t)(p0 + r0) * 128 + kk + s0_);
    gl16(&As[(256 + tid) * 8], A  + (size_t)(64 + r0) * 128 + kk + s0_);
    gl16(&Bs[(256 + tid) * 8], Bt + (size_t)(p0 + 64 + r0) * 128 + kk + s0_);
    __syncthreads();
    bf16x8 af[4], bfv[4];
#pragma unroll
    for (int i = 0; i < 4; ++i)
      af[i] = *(const bf16x8*)&As[(wr * 64 + i * 16 + l16) * 32 + q4 * 8];
#pragma unroll
    for (int j = 0; j < 4; ++j)
      bfv[j] = *(const bf16x8*)&Bs[(wc * 64 + j * 16 + l16) * 32 + q4 * 8];
#pragma unroll
    for (int i = 0; i < 4; ++i)
#pragma unroll
      for (int j = 0; j < 4; ++j)
        acc[i][j] = __builtin_amdgcn_mfma_f32_16x16x32_bf16(af[i], bfv[j], acc[i][j], 0, 0, 0);
  }

  // rel-shift: (r,p) -> (c,k): flat r*384+p == c*383+k, drop c >= 128
#pragma unroll
  for (int i = 0; i < 4; ++i)
#pragma unroll
    for (int j = 0; j < 4; ++j)
#pragma unroll
      for (int rg = 0; rg < 4; ++rg) {
        int r = wr * 64 + i * 16 + q4 * 4 + rg;
        int p = p0 + wc * 64 + j * 16 + l16;
        int t = r + p;
        int c = (t < 383) ? r : (r + 1);
        int k = (t < 383) ? t : (t - 383);
        if (c < 128) {
          int tt = k >> 7, jj = (k >> 4) & 7, ll = k & 15;
          int wa = c >> 5, ia = (c >> 4) & 1, qa = (c >> 2) & 3, ra = c & 3;
          bdo[((((size_t)tt * 8 + jj) * 256) + wa * 64 + qa * 16 + ll) * 8 + ia * 4 + ra] =
              f2bf(acc[i][j][rg]);
        }
      }
}

// ---------------------------------------------------------------------------
// fused local attention, 64-query-row blocks: one WG per (n,h,qh) for fixed b.
// grid 1024. LDS 50.2 KB -> 3 blocks/CU.
__global__ __launch_bounds__(256, 3)
void attn_k(const short* __restrict__ qb_b, const short* __restrict__ kpad,
            const short* __restrict__ vpadT, const short* __restrict__ bds,
            short* __restrict__ attnout, int b) {
  __shared__ __align__(16) short Ks[4 * 128 * 32]; // slabs [dc][row][32], reused Q->K->V
  __shared__ __align__(16) short Ps[64 * 136];     // 64-row P tile, padded stride

  const int tid = threadIdx.x;
  const int lane = tid & 63, wid = tid >> 6;
  const int q4 = lane >> 4, l16 = lane & 15;
  const int bx = blockIdx.x;          // (n*8 + h)*2 + qh
  const int qh = bx & 1, nh = bx >> 1;
  const int n = nh >> 3, h = nh & 7;

  const short* qtile = qb_b + (size_t)nh * 16384 + qh * 64 * 128;
  const short* kbase = kpad + ((size_t)(b * 8 + h) * 8448 + n * 128) * 128;
  const short* vtb = vpadT + (size_t)(b * 8 + h) * 128 * 8448 + n * 128;
  const short* bdb = bds + (size_t)nh * 49152;

  // stage this half's Q (64x128) into Ks, pull fragments to registers
#pragma unroll
  for (int it = 0; it < 4; ++it) {
    int ci = it * 256 + tid;                     // [0,1024)
    int dc = ci >> 8, rr = (ci >> 2) & 63, sub = (ci & 3) * 8;
    gl16(&Ks[ci * 8], qtile + rr * 128 + dc * 32 + sub);
  }
  __syncthreads();
  bf16x8 qf[4];
#pragma unroll
  for (int dc = 0; dc < 4; ++dc)
    qf[dc] = *(const bf16x8*)&Ks[dc * 2048 + (wid * 16 + l16) * 32 + q4 * 8];

  const f32x4 z4 = {0.f, 0.f, 0.f, 0.f};
  f32x4 acco[8];
#pragma unroll
  for (int j = 0; j < 8; ++j) acco[j] = z4;
  float rsum[4] = {};

  for (int t = 0; t < 3; ++t) {
    __syncthreads();  // (A) Ks/Ps free
#pragma unroll
    for (int it = 0; it < 8; ++it) {  // stage K tile (full 128 keys)
      int ci = it * 256 + tid;
      int dc = ci >> 9, rr = (ci >> 2) & 127, sub = (ci & 3) * 8;
      gl16(&Ks[ci * 8], kbase + (size_t)(t * 128 + rr) * 128 + dc * 32 + sub);
    }

    // bd fragment loads (8B per lane, this wave's ia-half only)
    s16x4 bdv[8];
#pragma unroll
    for (int j = 0; j < 8; ++j)
      bdv[j] = *(const s16x4*)&bdb[((((size_t)t * 8 + j) * 256) +
                 (qh * 2 + (wid >> 1)) * 64 + q4 * 16 + l16) * 8 + (wid & 1) * 4];

    __syncthreads();  // (B) K ready

    // S = Q @ K^T  (16 rows per wave)
    f32x4 accs[8];
#pragma unroll
    for (int j = 0; j < 8; ++j) accs[j] = z4;
#pragma unroll
    for (int dc = 0; dc < 4; ++dc) {
      bf16x8 kf[8];
#pragma unroll
      for (int j = 0; j < 8; ++j)
        kf[j] = *(const bf16x8*)&Ks[dc * 4096 + (j * 16 + l16) * 32 + q4 * 8];
#pragma unroll
      for (int j = 0; j < 8; ++j)
        accs[j] = __builtin_amdgcn_mfma_f32_16x16x32_bf16(qf[dc], kf[j], accs[j], 0, 0, 0);
    }

    // logits: s = ac + bd;  w = exp2(-100*log2e / (exp2(s*2*log2e/50) + 1))
#pragma unroll
    for (int j = 0; j < 8; ++j) {
      const int kg = t * 128 + j * 16 + l16;
#pragma unroll
      for (int rg = 0; rg < 4; ++rg) {
        float sv = accs[j][rg] + bf2f((unsigned short)bdv[j][rg]);
        float tt = exp2f(sv * 0.057707801635558534f);
        float wgt = exp2f(-144.26950408889634f * __fdividef(1.0f, tt + 1.0f));
        wgt = (kg < 383) ? wgt : 0.0f;
        accs[j][rg] = wgt;
        rsum[rg] += wgt;
      }
    }
    __syncthreads();  // (C) all waves done reading Ks (K tile)

    // stage V^T tile into Ks slabs [kc][d][32keys]; write P to Ps
#pragma unroll
    for (int it = 0; it < 8; ++it) {
      int ci = it * 256 + tid;
      int kc = ci >> 9, dd = (ci >> 2) & 127, sub = (ci & 3) * 8;
      gl16(&Ks[ci * 8], vtb + (size_t)dd * 8448 + t * 128 + kc * 32 + sub);
    }
#pragma unroll
    for (int j = 0; j < 8; ++j)
#pragma unroll
      for (int rg = 0; rg < 4; ++rg) {
        int c = wid * 16 + q4 * 4 + rg;
        int kl = j * 16 + l16;
        Ps[c * 136 + kl] = f2bf(accs[j][rg]);
      }
    __syncthreads();  // (D) V + P ready

    // PV over kc = 0..3
#pragma unroll
    for (int kc = 0; kc < 4; ++kc) {
      bf16x8 pf, vf[8];
      pf = *(const bf16x8*)&Ps[(wid * 16 + l16) * 136 + kc * 32 + q4 * 8];
#pragma unroll
      for (int j = 0; j < 8; ++j)
        vf[j] = *(const bf16x8*)&Ks[kc * 4096 + (j * 16 + l16) * 32 + q4 * 8];
#pragma unroll
      for (int j = 0; j < 8; ++j)
        acco[j] = __builtin_amdgcn_mfma_f32_16x16x32_bf16(pf, vf[j], acco[j], 0, 0, 0);
    }
  }

  // row-sum butterfly over the 16-lane group (cols), normalize, write bf16
  float rinv[4];
#pragma unroll
  for (int rg = 0; rg < 4; ++rg) {
    float rs = rsum[rg];
    rs += __shfl_xor(rs, 1);
    rs += __shfl_xor(rs, 2);
    rs += __shfl_xor(rs, 4);
    rs += __shfl_xor(rs, 8);
    rinv[rg] = __fdividef(1.0f, rs);
  }
#pragma unroll
  for (int j = 0; j < 8; ++j)
#pragma unroll
    for (int rg = 0; rg < 4; ++rg) {
      int srow = n * 128 + qh * 64 + wid * 16 + q4 * 4 + rg;
      int col = h * 128 + j * 16 + l16;
      attnout[((size_t)b * 8192 + srow) * 1024 + col] = f2bf(acco[j][rg] * rinv[rg]);
    }
}

// ---------------------------------------------------------------------------
extern "C" void kernel_launch(void* const* d_in, const int* in_sizes, int n_in,
                              void* d_out, int out_size, void* d_ws, size_t ws_size,
                              hipStream_t stream) {
  (void)in_sizes; (void)n_in; (void)out_size; (void)ws_size;
  const float* hs    = (const float*)d_in[0];
  const float* pemb  = (const float*)d_in[1];
  const float* Wq    = (const float*)d_in[2];
  const float* Wk    = (const float*)d_in[3];
  const float* Wv    = (const float*)d_in[4];
  const float* Wrel  = (const float*)d_in[5];
  const float* Wpost = (const float*)d_in[6];
  const float* pds   = (const float*)d_in[7];
  float* out = (float*)d_out;

  char* w = (char*)d_ws;
  auto alloc = [&](size_t bytes) -> char* {
    char* p = w; w += (bytes + 255) & ~(size_t)255; return p;
  };
  short* hs_bf   = (short*)alloc((size_t)16384 * 1024 * 2); // 33.5 MB (attnout aliases later)
  short* pos_bf  = (short*)alloc((size_t)384 * 1024 * 2);
  short* Wq_t    = (short*)alloc((size_t)1024 * 1024 * 2);  // Wq_t/Wk_t/Wv_t contiguous = Bt3
  short* Wk_t    = (short*)alloc((size_t)1024 * 1024 * 2);
  short* Wv_t    = (short*)alloc((size_t)1024 * 1024 * 2);
  short* Wrel_t  = (short*)alloc((size_t)1024 * 1024 * 2);
  short* Wpost_t = (short*)alloc((size_t)1024 * 1024 * 2);
  float* qsc     = (float*)alloc(512);
  short* q_bf    = (short*)alloc((size_t)2 * 64 * 8 * 128 * 128 * 2); // 33.5 MB
  short* kpad    = (short*)alloc((size_t)2 * 8 * 8448 * 128 * 2);     // 34.6 MB
  short* vpadT   = (short*)alloc((size_t)2 * 8 * 128 * 8448 * 2);     // 34.6 MB
  short* relk    = (short*)alloc((size_t)8 * 384 * 128 * 2);
  short* bds     = (short*)alloc((size_t)64 * 8 * 128 * 384 * 2);     // 50.3 MB, per-b (reused)
  short* attnout = hs_bf;  // hs_bf dead after QKV projection; attn starts after
  // total ~199 MB (< 232 MB known-good)

  const float kscale = (float)(log1p(exp(1.0)) / log(2.0));
  const double qsb = (1.0 / sqrt(128.0)) / log(2.0);

  cvt_bf16_k<<<16384, 256, 0, stream>>>(hs, hs_bf, 16384 * 1024);
  cvt_bf16_k<<<384, 256, 0, stream>>>(pemb, pos_bf, 384 * 1024);
  dim3 tg(16, 16);
  wtrans_k<<<tg, 256, 0, stream>>>(Wq, Wq_t);
  wtrans_k<<<tg, 256, 0, stream>>>(Wk, Wk_t);
  wtrans_k<<<tg, 256, 0, stream>>>(Wv, Wv_t);
  wtrans_k<<<tg, 256, 0, stream>>>(Wrel, Wrel_t);
  wtrans_k<<<tg, 256, 0, stream>>>(Wpost, Wpost_t);
  qscale_k<<<1, 128, 0, stream>>>(pds, qsc, qsb);
  hipMemsetAsync(kpad, 0, (size_t)2 * 8 * 8448 * 128 * 2, stream);
  vpadzero_k<<<2048, 256, 0, stream>>>(vpadT);

  qkv_fused_k<<<3072, 256, 0, stream>>>(hs_bf, Wq_t, q_bf, kpad, vpadT, qsc, kscale);
  rel_gemm_k<<<dim3(3, 8), 256, 0, stream>>>(pos_bf, Wrel_t, relk);

  for (int b = 0; b < 2; ++b) {
    const short* qb_b = q_bf + (size_t)b * 64 * 8 * 128 * 128;
    bd_gemm_k<<<dim3(3, 512), 256, 0, stream>>>(qb_b, relk, bds);
    attn_k<<<1024, 256, 0, stream>>>(qb_b, kpad, vpadT, bds, attnout, b);
  }

  post_gemm_k<<<1024, 256, 0, stream>>>(attnout, Wpost_t, out);
}